// Round 1
// 6250.307 us; speedup vs baseline: 2.2650x; 2.2650x over previous
//
#include <hip/hip_runtime.h>
#include <hip/hip_bf16.h>

#define SS 2048
#define EE 1024
#define FF 4096
#define HH 8
#define DD 128
#define LL 4
#define VV 32000

typedef short bf16x8 __attribute__((ext_vector_type(8)));
typedef short short4v __attribute__((ext_vector_type(4)));
typedef float f32x4 __attribute__((ext_vector_type(4)));

static __device__ __forceinline__ short f2bf(float f) {
  unsigned u = __builtin_bit_cast(unsigned, f);
  u += 0x7fffu + ((u >> 16) & 1u);   // round-to-nearest-even
  return (short)(u >> 16);
}

// ---------------------------------------------------------------------------
// Embedding gather: h[s,e] = emb[x[s], e]   (all fp32)
// ---------------------------------------------------------------------------
__global__ void embed_kernel(const int* __restrict__ x,
                             const float* __restrict__ emb,
                             float* __restrict__ h) {
  const int s = blockIdx.x;
  const int row = x[s];
  const float* src = emb + (long)row * EE;
  float* dst = h + (long)s * EE;
  for (int e = threadIdx.x; e < EE; e += blockDim.x)
    dst[e] = src[e];
}

// ---------------------------------------------------------------------------
// MFMA bf16 GEMM: C[M,N] = A[M,K] x B  (A,B fp32 in HBM, rounded to bf16 in
// LDS staging; fp32 accumulate).  BLAYOUT==0: B is [N,K] (NT); ==1: [K,N].
// CMODE: 0 = fp32 [M,N] out; 1 = bf16 [M,N] out; 2 = bf16 transposed [N,M].
// 128x128 tile, BK=32, 256 threads = 4 waves (2x2), each wave 64x64 via
// 4x4 v_mfma_f32_16x16x32_bf16.
// ---------------------------------------------------------------------------
template <int BLAYOUT, int RELU, int CMODE>
__global__ __launch_bounds__(256) void gemm_kernel(
    const float* __restrict__ A, const float* __restrict__ B,
    float* __restrict__ C, int M, int N, int K) {
  __shared__ __align__(16) short As[128][32];
  __shared__ __align__(16) short Bs[128][32];  // [n][k]

  const int tid = threadIdx.x;
  const long bm = (long)blockIdx.y * 128;
  const long bn = (long)blockIdx.x * 128;
  const int wave = tid >> 6;
  const int lane = tid & 63;
  const int wm = (wave >> 1) * 64;
  const int wn = (wave & 1) * 64;
  const int lr = lane & 15;    // row (A) / col (B,C)
  const int quad = lane >> 4;  // 0..3

  f32x4 acc[4][4] = {};

  for (int k0 = 0; k0 < K; k0 += 32) {
    // ---- stage A: fp32 -> bf16, [128][32]
    {
      const int chunk = tid & 7;   // 4-float k-chunk
      const int r0 = tid >> 3;     // 0..31
#pragma unroll
      for (int rr = 0; rr < 4; rr++) {
        const int r = r0 + rr * 32;
        const float4 va =
            *reinterpret_cast<const float4*>(A + (bm + r) * (long)K + k0 + chunk * 4);
        short* dst = &As[r][chunk * 4];
        dst[0] = f2bf(va.x);
        dst[1] = f2bf(va.y);
        dst[2] = f2bf(va.z);
        dst[3] = f2bf(va.w);
      }
    }
    // ---- stage B: fp32 -> bf16
    if (BLAYOUT == 0) {  // NT: B[N,K]
      const int chunk = tid & 7;   // k-chunk of 4
      const int r0 = tid >> 3;     // 0..31
#pragma unroll
      for (int rr = 0; rr < 4; rr++) {
        const int r = r0 + rr * 32;
        const float4 vb =
            *reinterpret_cast<const float4*>(B + (bn + r) * (long)K + k0 + chunk * 4);
        short* dst = &Bs[r][chunk * 4];
        dst[0] = f2bf(vb.x);
        dst[1] = f2bf(vb.y);
        dst[2] = f2bf(vb.z);
        dst[3] = f2bf(vb.w);
      }
    } else {  // NN: B[K,N] -> transpose-scatter into [n][k]
      const int chunk = tid & 31;  // n-chunk of 4 (128 cols)
      const int kr0 = tid >> 5;    // 0..7
#pragma unroll
      for (int rr = 0; rr < 4; rr++) {
        const int kr = kr0 + rr * 8;
        const float4 vb =
            *reinterpret_cast<const float4*>(B + (long)(k0 + kr) * N + bn + chunk * 4);
        Bs[chunk * 4 + 0][kr] = f2bf(vb.x);
        Bs[chunk * 4 + 1][kr] = f2bf(vb.y);
        Bs[chunk * 4 + 2][kr] = f2bf(vb.z);
        Bs[chunk * 4 + 3][kr] = f2bf(vb.w);
      }
    }
    __syncthreads();

    bf16x8 af[4], bfr[4];
#pragma unroll
    for (int mi = 0; mi < 4; mi++)
      af[mi] = *reinterpret_cast<const bf16x8*>(&As[wm + mi * 16 + lr][quad * 8]);
#pragma unroll
    for (int ni = 0; ni < 4; ni++)
      bfr[ni] = *reinterpret_cast<const bf16x8*>(&Bs[wn + ni * 16 + lr][quad * 8]);
#pragma unroll
    for (int mi = 0; mi < 4; mi++)
#pragma unroll
      for (int ni = 0; ni < 4; ni++)
        acc[mi][ni] = __builtin_amdgcn_mfma_f32_16x16x32_bf16(af[mi], bfr[ni],
                                                              acc[mi][ni], 0, 0, 0);
    __syncthreads();
  }

  // ---- epilogue; C/D layout: col = lane&15, row = quad*4 + reg
  if (CMODE == 0) {
#pragma unroll
    for (int mi = 0; mi < 4; mi++) {
#pragma unroll
      for (int ni = 0; ni < 4; ni++) {
#pragma unroll
        for (int r = 0; r < 4; r++) {
          const long row = bm + wm + mi * 16 + quad * 4 + r;
          const long col = bn + wn + ni * 16 + lr;
          float v = acc[mi][ni][r];
          if (RELU) v = fmaxf(v, 0.0f);
          C[row * (long)N + col] = v;
        }
      }
    }
  } else if (CMODE == 1) {  // bf16, normal layout
    short* Cs = (short*)C;
#pragma unroll
    for (int mi = 0; mi < 4; mi++) {
#pragma unroll
      for (int ni = 0; ni < 4; ni++) {
#pragma unroll
        for (int r = 0; r < 4; r++) {
          const long row = bm + wm + mi * 16 + quad * 4 + r;
          const long col = bn + wn + ni * 16 + lr;
          Cs[row * (long)N + col] = f2bf(acc[mi][ni][r]);
        }
      }
    }
  } else {  // CMODE == 2: bf16, transposed [N][M] — acc's 4 regs = 4
            // consecutive M-rows = 4 consecutive transposed cols -> short4
    short* Cs = (short*)C;
#pragma unroll
    for (int mi = 0; mi < 4; mi++) {
#pragma unroll
      for (int ni = 0; ni < 4; ni++) {
        const long colT = bn + wn + ni * 16 + lr;        // row of C^T
        const long row0 = bm + wm + mi * 16 + quad * 4;  // col of C^T (x4)
        short4v t;
        t[0] = f2bf(acc[mi][ni][0]);
        t[1] = f2bf(acc[mi][ni][1]);
        t[2] = f2bf(acc[mi][ni][2]);
        t[3] = f2bf(acc[mi][ni][3]);
        *reinterpret_cast<short4v*>(Cs + colT * (long)M + row0) = t;
      }
    }
  }
}

// ---------------------------------------------------------------------------
// Flash attention, bf16 MFMA.  q,k: bf16 [S][H*D]; vT: bf16 [H*D][S];
// o: fp32 [S][H*D].  No 1/sqrt(D) scale (reference has none).
// Block = (64-row Q tile, head); 4 waves x 16 rows; KV tiles of 64.
// Score layout (C of 16x16x32): col=lane&15 (kv), row=quad*4+reg (q).
// Row stats (m,l) live per-lane for the quad's 4 rows; 16-lane shfl_xor
// reduces across the kv direction.
// ---------------------------------------------------------------------------
#define QB 64
#define KVB 64

__global__ __launch_bounds__(256) void attn_kernel(const short* __restrict__ q,
                                                   const short* __restrict__ k,
                                                   const short* __restrict__ vT,
                                                   float* __restrict__ o) {
  __shared__ __align__(16) short Ks[KVB][136];  // [kv][d], pad 8 -> even banks
  __shared__ __align__(16) short Vt[DD][72];    // [d][kv], pad 8
  __shared__ __align__(16) short Ps[QB][72];    // [q][kv], pad 8 (intra-wave)

  const int qt = blockIdx.x;
  const int h = blockIdx.y;
  const int s0 = qt * QB;
  const int tid = threadIdx.x;
  const int lane = tid & 63;
  const int wave = tid >> 6;
  const int lr = lane & 15;
  const int qd = lane >> 4;
  const int wm = wave * 16;

  // Q fragments (A-layout): row = s0+wm+lr, k-slices d = kk*32 + qd*8 .. +7
  bf16x8 qf[4];
  {
    const short* Qr = q + (long)(s0 + wm + lr) * (HH * DD) + h * DD;
#pragma unroll
    for (int kk = 0; kk < 4; kk++)
      qf[kk] = *reinterpret_cast<const bf16x8*>(Qr + kk * 32 + qd * 8);
  }

  float m[4], l[4];
  f32x4 accO[8] = {};
#pragma unroll
  for (int r = 0; r < 4; r++) { m[r] = -3.0e38f; l[r] = 0.0f; }

  const int ntile = qt + 1;  // causal: kv tiles 0..qt
  for (int it = 0; it < ntile; it++) {
    const int kv0 = it * KVB;
    // ---- stage K tile [64][128] bf16 (coalesced 16B/lane)
    {
      const int c = tid & 15, r0 = tid >> 4;
#pragma unroll
      for (int rr = 0; rr < 4; rr++) {
        const int row = r0 + rr * 16;
        bf16x8 kv8 = *reinterpret_cast<const bf16x8*>(
            k + (long)(kv0 + row) * (HH * DD) + h * DD + c * 8);
        *reinterpret_cast<bf16x8*>(&Ks[row][c * 8]) = kv8;
      }
    }
    // ---- stage V^T tile [128][64] bf16 (vT is d-major -> coalesced)
    {
      const int c = tid & 7, d0 = tid >> 3;
#pragma unroll
      for (int rr = 0; rr < 4; rr++) {
        const int d = d0 + rr * 32;
        bf16x8 vv = *reinterpret_cast<const bf16x8*>(
            vT + (long)(h * DD + d) * SS + kv0 + c * 8);
        *reinterpret_cast<bf16x8*>(&Vt[d][c * 8]) = vv;
      }
    }
    __syncthreads();

    // ---- S = Q K^T  (per wave: 16 q-rows x 64 kv)
    f32x4 accS[4] = {};
#pragma unroll
    for (int ni = 0; ni < 4; ni++)
#pragma unroll
      for (int kk = 0; kk < 4; kk++) {
        bf16x8 kf =
            *reinterpret_cast<const bf16x8*>(&Ks[ni * 16 + lr][kk * 32 + qd * 8]);
        accS[ni] =
            __builtin_amdgcn_mfma_f32_16x16x32_bf16(qf[kk], kf, accS[ni], 0, 0, 0);
      }

    // ---- causal mask (only the diagonal tile: kv0 == s0)
    if (it == ntile - 1) {
      const int rowl = wm + qd * 4;  // + r
#pragma unroll
      for (int ni = 0; ni < 4; ni++) {
        const int col = ni * 16 + lr;
#pragma unroll
        for (int r = 0; r < 4; r++)
          if (col > rowl + r) accS[ni][r] = -3.0e38f;
      }
    }

    // ---- online softmax: row max across ni and the 16 kv-lanes
    float scale[4];
#pragma unroll
    for (int r = 0; r < 4; r++) {
      float x = fmaxf(fmaxf(accS[0][r], accS[1][r]),
                      fmaxf(accS[2][r], accS[3][r]));
#pragma unroll
      for (int off = 1; off < 16; off <<= 1) x = fmaxf(x, __shfl_xor(x, off));
      const float mn = fmaxf(m[r], x);
      scale[r] = __expf(m[r] - mn);
      m[r] = mn;
    }

    // ---- p = exp(s - m); write P to LDS (bf16); row sums
    float rs[4] = {0.f, 0.f, 0.f, 0.f};
#pragma unroll
    for (int ni = 0; ni < 4; ni++) {
#pragma unroll
      for (int r = 0; r < 4; r++) {
        const float p = __expf(accS[ni][r] - m[r]);
        rs[r] += p;
        Ps[wm + qd * 4 + r][ni * 16 + lr] = f2bf(p);
      }
    }
#pragma unroll
    for (int r = 0; r < 4; r++) {
#pragma unroll
      for (int off = 1; off < 16; off <<= 1) rs[r] += __shfl_xor(rs[r], off);
      l[r] = l[r] * scale[r] + rs[r];
#pragma unroll
      for (int ni = 0; ni < 8; ni++) accO[ni][r] *= scale[r];
    }

    // ---- O += P V  (P read back in A-layout; intra-wave rows only, no barrier)
    bf16x8 pa[2];
#pragma unroll
    for (int kk = 0; kk < 2; kk++)
      pa[kk] = *reinterpret_cast<const bf16x8*>(&Ps[wm + lr][kk * 32 + qd * 8]);
#pragma unroll
    for (int ni = 0; ni < 8; ni++)
#pragma unroll
      for (int kk = 0; kk < 2; kk++) {
        bf16x8 bv =
            *reinterpret_cast<const bf16x8*>(&Vt[ni * 16 + lr][kk * 32 + qd * 8]);
        accO[ni] =
            __builtin_amdgcn_mfma_f32_16x16x32_bf16(pa[kk], bv, accO[ni], 0, 0, 0);
      }
    __syncthreads();  // all waves done with Ks/Vt before restage
  }

  // ---- epilogue: o = accO / l
#pragma unroll
  for (int r = 0; r < 4; r++) {
    const float inv = 1.0f / l[r];
    const long row = s0 + wm + qd * 4 + r;
#pragma unroll
    for (int ni = 0; ni < 8; ni++)
      o[row * (HH * DD) + h * DD + ni * 16 + lr] = accO[ni][r] * inv;
  }
}

// ---------------------------------------------------------------------------
extern "C" void kernel_launch(void* const* d_in, const int* in_sizes, int n_in,
                              void* d_out, int out_size, void* d_ws, size_t ws_size,
                              hipStream_t stream) {
  const int* x = (const int*)d_in[0];
  const float* emb = (const float*)d_in[1];
  const float* ff_w = (const float*)d_in[2];
  const float* q_w = (const float*)d_in[3];
  const float* k_w = (const float*)d_in[4];
  const float* v_w = (const float*)d_in[5];
  const float* o_w = (const float*)d_in[6];

  // workspace layout: h fp32 (8MB) | hf fp32 (32MB, o aliases) |
  //                   q bf16 (4MB) | k bf16 (4MB) | vT bf16 (4MB) = 52 MB
  char* wsb = (char*)d_ws;
  float* h = (float*)wsb;
  float* hf = (float*)(wsb + (size_t)SS * EE * 4);
  float* o = hf;  // hf is dead after the V projection
  short* qb = (short*)(wsb + (size_t)SS * EE * 4 + (size_t)SS * FF * 4);
  short* kb = qb + (size_t)SS * EE;
  short* vb = kb + (size_t)SS * EE;  // transposed [E][S]

  embed_kernel<<<SS, 256, 0, stream>>>(x, emb, h);

  for (int i = 0; i < LL; i++) {
    // hf = relu(h @ ff_w[i])   [2048,1024]x[1024,4096], fp32 out
    gemm_kernel<1, 1, 0><<<dim3(FF / 128, SS / 128), 256, 0, stream>>>(
        h, ff_w + (size_t)i * EE * FF, hf, SS, FF, EE);
    // q/k = hf @ {q,k}_w[i] -> bf16 [S][E];  v -> bf16 transposed [E][S]
    gemm_kernel<1, 0, 1><<<dim3(EE / 128, SS / 128), 256, 0, stream>>>(
        hf, q_w + (size_t)i * FF * EE, (float*)qb, SS, EE, FF);
    gemm_kernel<1, 0, 1><<<dim3(EE / 128, SS / 128), 256, 0, stream>>>(
        hf, k_w + (size_t)i * FF * EE, (float*)kb, SS, EE, FF);
    gemm_kernel<1, 0, 2><<<dim3(EE / 128, SS / 128), 256, 0, stream>>>(
        hf, v_w + (size_t)i * FF * EE, (float*)vb, SS, EE, FF);
    // flash attention (writes o = hf region; hf dead from here)
    attn_kernel<<<dim3(SS / QB, HH), 256, 0, stream>>>(qb, kb, vb, o);
    // h = o @ o_w[i]   [2048,1024]x[1024,1024]
    gemm_kernel<1, 0, 0><<<dim3(EE / 128, SS / 128), 256, 0, stream>>>(
        o, o_w + (size_t)i * EE * EE, h, SS, EE, EE);
  }

  // logits = h @ emb^T  (NT: emb is [V,E]), fp32 out
  gemm_kernel<0, 0, 0><<<dim3(VV / 128, SS / 128), 256, 0, stream>>>(
      h, emb, (float*)d_out, SS, VV, EE);
}

// Round 2
// 1626.295 us; speedup vs baseline: 8.7049x; 3.8433x over previous
//
#include <hip/hip_runtime.h>
#include <hip/hip_bf16.h>

#define SS 2048
#define EE 1024
#define FF 4096
#define HH 8
#define DD 128
#define LL 4
#define VV 32000
#define QKS 2048   // row stride (shorts) of fused q|k activation buffer

typedef short bf16x8 __attribute__((ext_vector_type(8)));
typedef short short4v __attribute__((ext_vector_type(4)));
typedef float f32x4 __attribute__((ext_vector_type(4)));

static __device__ __forceinline__ short f2bf(float f) {
  unsigned u = __builtin_bit_cast(unsigned, f);
  u += 0x7fffu + ((u >> 16) & 1u);   // round-to-nearest-even
  return (short)(u >> 16);
}

static __device__ __forceinline__ void gload_lds16(const short* g, short* l) {
  __builtin_amdgcn_global_load_lds(
      (const __attribute__((address_space(1))) void*)g,
      (__attribute__((address_space(3))) void*)l, 16, 0, 0);
}

// ---------------------------------------------------------------------------
// Embedding gather: h[s,e] = bf16(emb[x[s], e])
// ---------------------------------------------------------------------------
__global__ void embed_kernel(const int* __restrict__ x,
                             const float* __restrict__ emb,
                             short* __restrict__ h) {
  const int s = blockIdx.x;
  const int row = x[s];
  const float* src = emb + (long)row * EE;
  short* dst = h + (long)s * EE;
  for (int e = threadIdx.x; e < EE; e += blockDim.x)
    dst[e] = f2bf(src[e]);
}

// ---------------------------------------------------------------------------
// Linear fp32 -> bf16 convert (n4 = count of float4)
// ---------------------------------------------------------------------------
__global__ void convert_kernel(const float* __restrict__ in,
                               short* __restrict__ out, long n4) {
  const long stride = (long)gridDim.x * blockDim.x;
  for (long i = (long)blockIdx.x * blockDim.x + threadIdx.x; i < n4; i += stride) {
    const float4 v = reinterpret_cast<const float4*>(in)[i];
    short4v s;
    s[0] = f2bf(v.x); s[1] = f2bf(v.y); s[2] = f2bf(v.z); s[3] = f2bf(v.w);
    reinterpret_cast<short4v*>(out)[i] = s;
  }
}

// ---------------------------------------------------------------------------
// Transpose + convert: in fp32 [R][C] -> out bf16 [C][R].  32x32 LDS tiles.
// ---------------------------------------------------------------------------
__global__ __launch_bounds__(256) void transpose_kernel(
    const float* __restrict__ in, short* __restrict__ out, int R, int C) {
  __shared__ short t[32][33];
  const int c0 = blockIdx.x * 32, r0 = blockIdx.y * 32;
  const int tx = threadIdx.x & 31, ty = threadIdx.x >> 5;  // ty 0..7
#pragma unroll
  for (int i = 0; i < 4; i++) {
    const int r = ty + i * 8;
    t[r][tx] = f2bf(in[(long)(r0 + r) * C + c0 + tx]);
  }
  __syncthreads();
#pragma unroll
  for (int i = 0; i < 4; i++) {
    const int rr = ty + i * 8;
    out[(long)(c0 + rr) * R + r0 + tx] = t[tx][rr];
  }
}

// q/k/v weights [F][E] -> qkvT [3][E][F] bf16, slot = blockIdx.z
__global__ __launch_bounds__(256) void transpose_qkv_kernel(
    const float* __restrict__ qw, const float* __restrict__ kw,
    const float* __restrict__ vw, short* __restrict__ out) {
  __shared__ short t[32][33];
  const float* in = blockIdx.z == 0 ? qw : (blockIdx.z == 1 ? kw : vw);
  short* o = out + (long)blockIdx.z * FF * EE;
  const int c0 = blockIdx.x * 32, r0 = blockIdx.y * 32;
  const int tx = threadIdx.x & 31, ty = threadIdx.x >> 5;
#pragma unroll
  for (int i = 0; i < 4; i++) {
    const int r = ty + i * 8;
    t[r][tx] = f2bf(in[(long)(r0 + r) * EE + c0 + tx]);
  }
  __syncthreads();
#pragma unroll
  for (int i = 0; i < 4; i++) {
    const int rr = ty + i * 8;
    o[(long)(c0 + rr) * FF + r0 + tx] = t[tx][rr];
  }
}

// ---------------------------------------------------------------------------
// bf16 NT GEMM (m97 structure): A bf16 [M][K], B bf16 [N][K], fp32 accum.
// 128x128 tile, BK=32, 256 thr = 4 waves (2x2), global_load_lds width 16.
// CMODE: 0 = fp32 [M][N]; 1 = bf16 [M][N]; 3 = fused QKV epilogue:
//        cols <2048 -> bf16 [M][QKS] (q|k), cols >=2048 -> bf16 [N-2048][M] (vT).
// ---------------------------------------------------------------------------
template <int RELU, int CMODE>
__global__ __launch_bounds__(256) void gemm_bf16(
    const short* __restrict__ A, const short* __restrict__ B,
    void* __restrict__ Cv, void* __restrict__ C2, int M, int N, int K) {
  __shared__ __align__(16) short As[128][32];
  __shared__ __align__(16) short Bs[128][32];

  const int tid = threadIdx.x;
  const int wave = tid >> 6, lane = tid & 63;
  const int lr = lane & 15, quad = lane >> 4;
  const int wm = (wave >> 1) * 64, wn = (wave & 1) * 64;
  const long bm = (long)blockIdx.y * 128, bn = (long)blockIdx.x * 128;

  // staging map: lane l -> row (l>>2), 16B chunk (l&3); wave w stages rows
  // [w*32, w*32+32).  LDS dest is wave-uniform base + lane*16 (HW rule).
  const int srow = lane >> 2;
  const int scol = (lane & 3) * 8;
  const short* Abase = A + (bm + wave * 32 + srow) * (long)K + scol;
  const short* Bbase = B + (bn + wave * 32 + srow) * (long)K + scol;

  f32x4 acc[4][4] = {};

  for (int k0 = 0; k0 < K; k0 += 32) {
#pragma unroll
    for (int j = 0; j < 2; j++) {
      gload_lds16(Abase + (long)j * 16 * K + k0, &As[wave * 32 + j * 16][0]);
      gload_lds16(Bbase + (long)j * 16 * K + k0, &Bs[wave * 32 + j * 16][0]);
    }
    __syncthreads();

    bf16x8 af[4], bfr[4];
#pragma unroll
    for (int mi = 0; mi < 4; mi++)
      af[mi] = *reinterpret_cast<const bf16x8*>(&As[wm + mi * 16 + lr][quad * 8]);
#pragma unroll
    for (int ni = 0; ni < 4; ni++)
      bfr[ni] = *reinterpret_cast<const bf16x8*>(&Bs[wn + ni * 16 + lr][quad * 8]);
#pragma unroll
    for (int mi = 0; mi < 4; mi++)
#pragma unroll
      for (int ni = 0; ni < 4; ni++)
        acc[mi][ni] = __builtin_amdgcn_mfma_f32_16x16x32_bf16(af[mi], bfr[ni],
                                                              acc[mi][ni], 0, 0, 0);
    __syncthreads();
  }

  // ---- epilogue; C/D layout: col = lane&15, row = quad*4 + reg
  if (CMODE == 0) {
    float* C = (float*)Cv;
#pragma unroll
    for (int mi = 0; mi < 4; mi++)
#pragma unroll
      for (int ni = 0; ni < 4; ni++)
#pragma unroll
        for (int r = 0; r < 4; r++) {
          const long row = bm + wm + mi * 16 + quad * 4 + r;
          const long col = bn + wn + ni * 16 + lr;
          float v = acc[mi][ni][r];
          if (RELU) v = fmaxf(v, 0.0f);
          C[row * (long)N + col] = v;
        }
  } else if (CMODE == 1) {
    short* C = (short*)Cv;
#pragma unroll
    for (int mi = 0; mi < 4; mi++)
#pragma unroll
      for (int ni = 0; ni < 4; ni++)
#pragma unroll
        for (int r = 0; r < 4; r++) {
          const long row = bm + wm + mi * 16 + quad * 4 + r;
          const long col = bn + wn + ni * 16 + lr;
          float v = acc[mi][ni][r];
          if (RELU) v = fmaxf(v, 0.0f);
          C[row * (long)N + col] = f2bf(v);
        }
  } else {  // CMODE == 3
    if (bn < 2048) {  // q|k region, bf16 [M][QKS]
      short* C = (short*)Cv;
#pragma unroll
      for (int mi = 0; mi < 4; mi++)
#pragma unroll
        for (int ni = 0; ni < 4; ni++)
#pragma unroll
          for (int r = 0; r < 4; r++) {
            const long row = bm + wm + mi * 16 + quad * 4 + r;
            const long col = bn + wn + ni * 16 + lr;
            C[row * QKS + col] = f2bf(acc[mi][ni][r]);
          }
    } else {  // v region -> transposed bf16 [E][M]; 4 regs = 4 contiguous cols
      short* C = (short*)C2;
#pragma unroll
      for (int mi = 0; mi < 4; mi++)
#pragma unroll
        for (int ni = 0; ni < 4; ni++) {
          const long colT = bn - 2048 + wn + ni * 16 + lr;   // vT row
          const long row0 = bm + wm + mi * 16 + quad * 4;    // vT col (x4)
          short4v t;
          t[0] = f2bf(acc[mi][ni][0]);
          t[1] = f2bf(acc[mi][ni][1]);
          t[2] = f2bf(acc[mi][ni][2]);
          t[3] = f2bf(acc[mi][ni][3]);
          *reinterpret_cast<short4v*>(C + colT * (long)M + row0) = t;
        }
    }
  }
}

// ---------------------------------------------------------------------------
// Flash attention, bf16 MFMA.  qk: bf16 [S][QKS] (q cols 0..1023, k cols
// 1024..2047); vT: bf16 [H*D][S]; o: bf16 [S][H*D].  No 1/sqrt(D) scale.
// Block = (64-row Q tile, head); 4 waves x 16 rows; KV tiles of 64.
// ---------------------------------------------------------------------------
#define QB 64
#define KVB 64

__global__ __launch_bounds__(256) void attn_kernel(const short* __restrict__ qk,
                                                   const short* __restrict__ vT,
                                                   short* __restrict__ o) {
  __shared__ __align__(16) short Ks[KVB][136];  // [kv][d], pad 8
  __shared__ __align__(16) short Vt[DD][72];    // [d][kv], pad 8
  __shared__ __align__(16) short Ps[QB][72];    // [q][kv], pad 8 (intra-wave)

  const int qt = blockIdx.x;
  const int h = blockIdx.y;
  const int s0 = qt * QB;
  const int tid = threadIdx.x;
  const int lane = tid & 63;
  const int wave = tid >> 6;
  const int lr = lane & 15;
  const int qd = lane >> 4;
  const int wm = wave * 16;

  // Q fragments (A-layout): row = s0+wm+lr, k-slices d = kk*32 + qd*8 .. +7
  bf16x8 qf[4];
  {
    const short* Qr = qk + (long)(s0 + wm + lr) * QKS + h * DD;
#pragma unroll
    for (int kk = 0; kk < 4; kk++)
      qf[kk] = *reinterpret_cast<const bf16x8*>(Qr + kk * 32 + qd * 8);
  }

  float m[4], l[4];
  f32x4 accO[8] = {};
#pragma unroll
  for (int r = 0; r < 4; r++) { m[r] = -3.0e38f; l[r] = 0.0f; }

  const int ntile = qt + 1;  // causal: kv tiles 0..qt
  for (int it = 0; it < ntile; it++) {
    const int kv0 = it * KVB;
    // ---- stage K tile [64][128] (k region = col offset EE in qk)
    {
      const int c = tid & 15, r0 = tid >> 4;
#pragma unroll
      for (int rr = 0; rr < 4; rr++) {
        const int row = r0 + rr * 16;
        bf16x8 kv8 = *reinterpret_cast<const bf16x8*>(
            qk + (long)(kv0 + row) * QKS + EE + h * DD + c * 8);
        *reinterpret_cast<bf16x8*>(&Ks[row][c * 8]) = kv8;
      }
    }
    // ---- stage V^T tile [128][64]
    {
      const int c = tid & 7, d0 = tid >> 3;
#pragma unroll
      for (int rr = 0; rr < 4; rr++) {
        const int d = d0 + rr * 32;
        bf16x8 vv = *reinterpret_cast<const bf16x8*>(
            vT + (long)(h * DD + d) * SS + kv0 + c * 8);
        *reinterpret_cast<bf16x8*>(&Vt[d][c * 8]) = vv;
      }
    }
    __syncthreads();

    // ---- S = Q K^T  (per wave: 16 q-rows x 64 kv)
    f32x4 accS[4] = {};
#pragma unroll
    for (int ni = 0; ni < 4; ni++)
#pragma unroll
      for (int kk = 0; kk < 4; kk++) {
        bf16x8 kf =
            *reinterpret_cast<const bf16x8*>(&Ks[ni * 16 + lr][kk * 32 + qd * 8]);
        accS[ni] =
            __builtin_amdgcn_mfma_f32_16x16x32_bf16(qf[kk], kf, accS[ni], 0, 0, 0);
      }

    // ---- causal mask (diagonal tile only)
    if (it == ntile - 1) {
      const int rowl = wm + qd * 4;
#pragma unroll
      for (int ni = 0; ni < 4; ni++) {
        const int col = ni * 16 + lr;
#pragma unroll
        for (int r = 0; r < 4; r++)
          if (col > rowl + r) accS[ni][r] = -3.0e38f;
      }
    }

    // ---- online softmax
    float scale[4];
#pragma unroll
    for (int r = 0; r < 4; r++) {
      float x = fmaxf(fmaxf(accS[0][r], accS[1][r]),
                      fmaxf(accS[2][r], accS[3][r]));
#pragma unroll
      for (int off = 1; off < 16; off <<= 1) x = fmaxf(x, __shfl_xor(x, off));
      const float mn = fmaxf(m[r], x);
      scale[r] = __expf(m[r] - mn);
      m[r] = mn;
    }

    float rs[4] = {0.f, 0.f, 0.f, 0.f};
#pragma unroll
    for (int ni = 0; ni < 4; ni++) {
#pragma unroll
      for (int r = 0; r < 4; r++) {
        const float p = __expf(accS[ni][r] - m[r]);
        rs[r] += p;
        Ps[wm + qd * 4 + r][ni * 16 + lr] = f2bf(p);
      }
    }
#pragma unroll
    for (int r = 0; r < 4; r++) {
#pragma unroll
      for (int off = 1; off < 16; off <<= 1) rs[r] += __shfl_xor(rs[r], off);
      l[r] = l[r] * scale[r] + rs[r];
#pragma unroll
      for (int ni = 0; ni < 8; ni++) accO[ni][r] *= scale[r];
    }

    // ---- O += P V  (intra-wave rows only, no barrier)
    bf16x8 pa[2];
#pragma unroll
    for (int kk = 0; kk < 2; kk++)
      pa[kk] = *reinterpret_cast<const bf16x8*>(&Ps[wm + lr][kk * 32 + qd * 8]);
#pragma unroll
    for (int ni = 0; ni < 8; ni++)
#pragma unroll
      for (int kk = 0; kk < 2; kk++) {
        bf16x8 bv =
            *reinterpret_cast<const bf16x8*>(&Vt[ni * 16 + lr][kk * 32 + qd * 8]);
        accO[ni] =
            __builtin_amdgcn_mfma_f32_16x16x32_bf16(pa[kk], bv, accO[ni], 0, 0, 0);
      }
    __syncthreads();
  }

  // ---- epilogue: o = bf16(accO / l)
#pragma unroll
  for (int r = 0; r < 4; r++) {
    const float inv = 1.0f / l[r];
    const long row = s0 + wm + qd * 4 + r;
#pragma unroll
    for (int ni = 0; ni < 8; ni++)
      o[row * EE + h * DD + ni * 16 + lr] = f2bf(accO[ni][r] * inv);
  }
}

// ---------------------------------------------------------------------------
extern "C" void kernel_launch(void* const* d_in, const int* in_sizes, int n_in,
                              void* d_out, int out_size, void* d_ws, size_t ws_size,
                              hipStream_t stream) {
  const int* x = (const int*)d_in[0];
  const float* emb = (const float*)d_in[1];
  const float* ff_w = (const float*)d_in[2];
  const float* q_w = (const float*)d_in[3];
  const float* k_w = (const float*)d_in[4];
  const float* v_w = (const float*)d_in[5];
  const float* o_w = (const float*)d_in[6];

  // workspace (bytes):
  //   h    @ 0      4 MB  bf16 [2048][1024]            (live throughout)
  //   hf/o @ 4 MB  16 MB  bf16 [2048][4096]            (o aliases hf)
  //   qk   @ 20 MB  8 MB  bf16 [2048][2048]
  //   vT   @ 28 MB  4 MB  bf16 [1024][2048]
  //   ffT  @ 32 MB  8 MB  bf16 [4096][1024]
  //   qkvT @ 40 MB 24 MB  bf16 [3][1024][4096]
  //   oT   @ 64 MB  2 MB  bf16 [1024][1024]
  //   embb @ 4 MB 62.5 MB bf16 [32000][1024]  (written AFTER layers; overlaps
  //                                            dead hf/qk/vT/ffT/qkvT/oT)
  char* wsb = (char*)d_ws;
  short* h    = (short*)(wsb);
  short* hf   = (short*)(wsb + (4L << 20));
  short* o    = hf;
  short* qk   = (short*)(wsb + (20L << 20));
  short* vT   = (short*)(wsb + (28L << 20));
  short* ffT  = (short*)(wsb + (32L << 20));
  short* qkvT = (short*)(wsb + (40L << 20));
  short* oT   = (short*)(wsb + (64L << 20));
  short* embb = (short*)(wsb + (4L << 20));

  embed_kernel<<<SS, 256, 0, stream>>>(x, emb, h);

  for (int i = 0; i < LL; i++) {
    // weight transposes -> bf16 NT layout
    transpose_kernel<<<dim3(FF / 32, EE / 32), 256, 0, stream>>>(
        ff_w + (size_t)i * EE * FF, ffT, EE, FF);
    transpose_qkv_kernel<<<dim3(EE / 32, FF / 32, 3), 256, 0, stream>>>(
        q_w + (size_t)i * FF * EE, k_w + (size_t)i * FF * EE,
        v_w + (size_t)i * FF * EE, qkvT);
    transpose_kernel<<<dim3(EE / 32, EE / 32), 256, 0, stream>>>(
        o_w + (size_t)i * EE * EE, oT, EE, EE);

    // hf = relu(h @ ff_w[i])   [2048,1024] x [4096,1024]^T -> bf16
    gemm_bf16<1, 1><<<dim3(FF / 128, SS / 128), 256, 0, stream>>>(
        h, ffT, hf, nullptr, SS, FF, EE);
    // fused q|k|v = hf @ qkv_w   [2048,4096] x [3072,4096]^T
    gemm_bf16<0, 3><<<dim3(3072 / 128, SS / 128), 256, 0, stream>>>(
        hf, qkvT, qk, vT, SS, 3072, FF);
    // flash attention (o overwrites hf region; hf dead)
    attn_kernel<<<dim3(SS / QB, HH), 256, 0, stream>>>(qk, vT, o);
    // h = o @ o_w[i]   [2048,1024] x [1024,1024]^T -> bf16
    gemm_bf16<0, 1><<<dim3(EE / 128, SS / 128), 256, 0, stream>>>(
        o, oT, h, nullptr, SS, EE, EE);
  }

  // emb -> bf16 (into now-dead per-layer region), then logits = h @ emb^T
  convert_kernel<<<2048, 256, 0, stream>>>(emb, embb, (long)VV * EE / 4);
  gemm_bf16<0, 0><<<dim3(VV / 128, SS / 128), 256, 0, stream>>>(
      h, embb, d_out, nullptr, SS, VV, EE);
}